// Round 9
// baseline (550.948 us; speedup 1.0000x reference)
//
#include <hip/hip_runtime.h>

// GraphRetriever on MI355X.
// R8 vs R7 (passed @521us): slot-looped k_gemm. 64-row m-tiles (782 blocks),
// A staged once per block (A HBM fetch 17x12.8MB-equivalent -> 12.8MB flat,
// no per-XCD duplication), loop s=0..16: DMA B-tile, MFMA, repack into a
// wave-private padded buffer (rows are per-wave -> no repack barriers),
// coalesced store. 2 barriers/slot. LDS 65.9KB -> 2 blocks/CU.
// Everything else unchanged from R7.

#define NN 50000
#define EE 800000
#define DD 128
#define RR 16
#define PP 256
#define PADN 50048          // 782*64
#define NSLOT 17            // 16 relations + self
#define CSTRIDE 136         // padded repack stride (shorts)

typedef __attribute__((ext_vector_type(4))) float f32x4;
typedef __attribute__((ext_vector_type(2))) float f32x2;
typedef __attribute__((ext_vector_type(8))) short s16x8;

__device__ __forceinline__ float bf2f(unsigned int u16v){
    unsigned int u = u16v << 16;
    return __builtin_bit_cast(float, u);
}
__device__ __forceinline__ unsigned short f2bf(float f){
    unsigned int u = __builtin_bit_cast(unsigned int, f);
    u = u + 0x7fffu + ((u >> 16) & 1u);
    return (unsigned short)(u >> 16);
}

// ---------------- CSR build ----------------
__global__ void k_hist(const int* __restrict__ dst, int* __restrict__ deg,
                       int* __restrict__ rank){
    int e = blockIdx.x*256 + threadIdx.x;
    if (e < EE) rank[e] = atomicAdd(&deg[dst[e]], 1);
}
__global__ void k_scan1(const int* __restrict__ deg, int* __restrict__ bsum){
    __shared__ int sm[256];
    int t = threadIdx.x, i = blockIdx.x*256 + t;
    sm[t] = (i < NN) ? deg[i] : 0;
    __syncthreads();
    for (int o = 128; o > 0; o >>= 1){
        if (t < o) sm[t] += sm[t+o];
        __syncthreads();
    }
    if (t == 0) bsum[blockIdx.x] = sm[0];
}
__global__ void k_scan2(const int* __restrict__ bsum, int* __restrict__ boff){
    __shared__ int sm[256];
    int t = threadIdx.x;
    int v = (t < 196) ? bsum[t] : 0;
    sm[t] = v;
    __syncthreads();
    for (int o = 1; o < 256; o <<= 1){
        int x = (t >= o) ? sm[t-o] : 0;
        __syncthreads();
        sm[t] += x;
        __syncthreads();
    }
    boff[t] = sm[t] - v;   // exclusive over blocks
}
__global__ void k_scan3(const int* __restrict__ deg, const int* __restrict__ boff,
                        int* __restrict__ row_start){
    __shared__ int sm[256];
    int t = threadIdx.x, i = blockIdx.x*256 + t;
    int v = (i < NN) ? deg[i] : 0;
    sm[t] = v;
    __syncthreads();
    for (int o = 1; o < 256; o <<= 1){
        int x = (t >= o) ? sm[t-o] : 0;
        __syncthreads();
        sm[t] += x;
        __syncthreads();
    }
    if (i < NN) row_start[i] = boff[blockIdx.x] + sm[t] - v;
    if (i == 0) row_start[NN] = EE;
}

// ---------------- fused: csr fill + x0 convert(+swizzle) + weight prep ----------------
#define NB_FILL 3125
#define NB_CVT  25024
#define NB_PREP 3968
__global__ void k_fused(const int* __restrict__ src, const int* __restrict__ dst,
                        const int* __restrict__ et, const int* __restrict__ row_start,
                        const int* __restrict__ rank, unsigned int* __restrict__ csr,
                        const float* __restrict__ nf, unsigned short* __restrict__ xb,
                        const float* __restrict__ W_rel, const float* __restrict__ W_self,
                        const float* __restrict__ Wihf, const float* __restrict__ Wihb,
                        const float* __restrict__ Whhf, const float* __restrict__ Whhb,
                        const float* __restrict__ Wop,  const float* __restrict__ Ws1,
                        unsigned short* __restrict__ Bcat,
                        float* __restrict__ Wiht, float* __restrict__ Whht,
                        float* __restrict__ Wopt, float* __restrict__ Ws1t){
    int b = blockIdx.x;
    if (b < NB_FILL){
        int e = b*256 + threadIdx.x;
        int pos = row_start[dst[e]] + rank[e];
        csr[pos] = ((unsigned int)et[e] << 16) | (unsigned int)src[e];  // src<50000<2^16
        return;
    }
    if (b < NB_FILL + NB_CVT){
        int i = (b - NB_FILL)*256 + threadIdx.x;   // < PADN*DD exactly
        int r  = i >> 7;
        int dd = i & 127;
        int d  = (((dd >> 3) ^ (r & 15)) << 3) | (dd & 7);   // swizzle decode
        xb[i] = (r < NN) ? f2bf(nf[(size_t)r*DD + d]) : (unsigned short)0;
        return;
    }
    int i = (b - NB_FILL - NB_CVT)*256 + threadIdx.x;
    if (i < 557056){   // Bcat[l][s][ko][dd], swizzled over dd-chunks by ko&15
        int l  = i / (NSLOT*DD*DD);
        int r  = i % (NSLOT*DD*DD);
        int s  = r / (DD*DD);
        int r2 = r % (DD*DD);
        int ko = r2 / DD;
        int dd = r2 % DD;
        int d  = (((dd >> 3) ^ (ko & 15)) << 3) | (dd & 7);
        float v = (s < RR) ? W_rel[(((size_t)(l*RR + s))*DD + d)*DD + ko]
                           : W_self[((size_t)l*DD + d)*DD + ko];
        Bcat[i] = f2bf(v);
        return;
    }
    int i2 = i - 557056;
    if (i2 < 131072){ int j=i2/512, g=i2%512; Wiht[i2] = Wihf[g*256+j]; }
    else if (i2 < 262144){ int i3=i2-131072; int j=i3/512, g=i3%512; Wiht[131072+i3] = Wihb[g*256+j]; }
    else if (i2 < 327680){ int i3=i2-262144; int j=i3/512, g=i3%512; Whht[i3] = Whhf[g*128+j]; }
    else if (i2 < 393216){ int i3=i2-327680; int j=i3/512, g=i3%512; Whht[65536+i3] = Whhb[g*128+j]; }
    else if (i2 < 425984){ int i3=i2-393216; int j=i3/128, k=i3%128; Wopt[i3] = Wop[k*256+j]; }
    else if (i2 < 458752){ int i3=i2-425984; int j=i3/128, k=i3%128; Ws1t[i3] = Ws1[k*256+j]; }
}

// ---------------- RGCN GEMM, slot-looped ----------------
// C[s][m][ko] = sum_d A[m][d] * Bt[s][ko][d]; A/Bt chunk-swizzled per row.
// 64-row m-tile per block; A staged once; loop 17 slots.
__global__ __launch_bounds__(256, 2) void k_gemm(const unsigned short* __restrict__ A,
                                                 const unsigned short* __restrict__ Bt,
                                                 unsigned short* __restrict__ C)
{
    __shared__ unsigned short As[64*128];       // 16KB, lives all slots
    __shared__ unsigned short Bs[128*128];      // 32KB, restaged per slot
    __shared__ unsigned short Cs[64*CSTRIDE];   // 17KB, wave-private rows
    const int m0 = blockIdx.x * 64;
    const int tid  = threadIdx.x;
    const int wave = tid >> 6;
    const int lane = tid & 63;

    // stage A rows [m0, m0+64): wave w -> rows [w*16, w*16+16), 4 x 1KB insts
    {
        const unsigned short* gA = A + ((size_t)m0 + wave*16)*DD + lane*8;
        unsigned short* lA = As + (wave*16)*DD;
        for (int i = 0; i < 4; ++i)
            __builtin_amdgcn_global_load_lds((__attribute__((address_space(1))) const void*)(gA + i*512),
                                             (__attribute__((address_space(3))) void*)(lA + i*512), 16, 0, 0);
    }

    for (int s = 0; s < NSLOT; ++s){
        __syncthreads();   // all waves done MFMA-reading Bs of slot s-1 (no-op cost at s=0)
        // stage B slot s: wave w -> rows [w*32, w*32+32), 8 x 1KB insts
        {
            const unsigned short* gB = Bt + ((size_t)s*DD + wave*32)*DD + lane*8;
            unsigned short* lB = Bs + (wave*32)*DD;
            for (int i = 0; i < 8; ++i)
                __builtin_amdgcn_global_load_lds((__attribute__((address_space(1))) const void*)(gB + i*512),
                                                 (__attribute__((address_space(3))) void*)(lB + i*512), 16, 0, 0);
        }
        __syncthreads();   // A (s=0) + B_s resident

        f32x4 acc[8];
        for (int t = 0; t < 8; ++t) acc[t] = (f32x4){0.f,0.f,0.f,0.f};
        for (int kb = 0; kb < 4; ++kb){
            const int cx = (((kb << 2) + (lane >> 4)) ^ (lane & 15)) << 3;
            s16x8 af = *(const s16x8*)(As + (wave*16 + (lane&15))*DD + cx);
            for (int nt = 0; nt < 8; ++nt){
                s16x8 bf = *(const s16x8*)(Bs + (nt*16 + (lane&15))*DD + cx);
                acc[nt] = __builtin_amdgcn_mfma_f32_16x16x32_bf16(af, bf, acc[nt], 0, 0, 0);
            }
        }
        // repack: wave w writes/reads only rows [w*16, w*16+16) -> no barrier
        int mrow0 = wave*16 + ((lane>>4)<<2);
        for (int nt = 0; nt < 8; ++nt){
            int coln = nt*16 + (lane&15);
            for (int r = 0; r < 4; ++r)
                Cs[(mrow0+r)*CSTRIDE + coln] = f2bf(acc[nt][r]);
        }
        for (int i = 0; i < 4; ++i){
            int u = i*64 + lane;           // 0..255 within wave's 16x16-chunk grid
            int row = wave*16 + (u >> 4);
            int seg = u & 15;
            int m = m0 + row;
            if (m < NN)
                *(s16x8*)(C + ((size_t)s*NN + m)*DD + seg*8) =
                    *(const s16x8*)(Cs + row*CSTRIDE + seg*8);
        }
    }
}

// ---------------- fused aggregate + self + bias + relu + LayerNorm ----------------
__global__ __launch_bounds__(256) void k_aggfin(
    const unsigned short* __restrict__ trans, const unsigned int* __restrict__ csr,
    const int* __restrict__ row_start,
    const float* __restrict__ bs, const float* __restrict__ lg, const float* __restrict__ lb,
    float* __restrict__ xf, unsigned short* __restrict__ xb, int write_f)
{
    int nd = blockIdx.x*4 + (threadIdx.x >> 6);
    int lane = threadIdx.x & 63;
    int half = lane >> 5;
    int sl   = lane & 31;
    if (nd >= NN){
        if (!write_f && nd < PADN) ((unsigned int*)xb)[(size_t)nd*64 + lane] = 0u;
        return;
    }
    int rs = row_start[nd], re = row_start[nd+1];
    float a0 = 0.f, a1 = 0.f, a2 = 0.f, a3 = 0.f;
    int e = rs + half;
    for (; e + 2 < re; e += 4){
        unsigned int v1 = csr[e], v2 = csr[e+2];
        unsigned long long p1 = *((const unsigned long long*)(trans +
            ((size_t)(v1 >> 16)*NN + (v1 & 0xffffu))*DD) + sl);
        unsigned long long p2 = *((const unsigned long long*)(trans +
            ((size_t)(v2 >> 16)*NN + (v2 & 0xffffu))*DD) + sl);
        unsigned int l1 = (unsigned int)p1, h1 = (unsigned int)(p1 >> 32);
        unsigned int l2 = (unsigned int)p2, h2 = (unsigned int)(p2 >> 32);
        a0 += bf2f(l1 & 0xffffu) + bf2f(l2 & 0xffffu);
        a1 += bf2f(l1 >> 16)     + bf2f(l2 >> 16);
        a2 += bf2f(h1 & 0xffffu) + bf2f(h2 & 0xffffu);
        a3 += bf2f(h1 >> 16)     + bf2f(h2 >> 16);
    }
    if (e < re){
        unsigned int v1 = csr[e];
        unsigned long long p1 = *((const unsigned long long*)(trans +
            ((size_t)(v1 >> 16)*NN + (v1 & 0xffffu))*DD) + sl);
        unsigned int l1 = (unsigned int)p1, h1 = (unsigned int)(p1 >> 32);
        a0 += bf2f(l1 & 0xffffu);
        a1 += bf2f(l1 >> 16);
        a2 += bf2f(h1 & 0xffffu);
        a3 += bf2f(h1 >> 16);
    }
    a0 += __shfl_xor(a0, 32);
    a1 += __shfl_xor(a1, 32);
    a2 += __shfl_xor(a2, 32);
    a3 += __shfl_xor(a3, 32);

    float invd = 1.f / fmaxf((float)(re - rs), 1.f);
    unsigned long long sv = *((const unsigned long long*)(trans +
        ((size_t)16*NN + nd)*DD) + sl);
    unsigned int slo = (unsigned int)sv, shi = (unsigned int)(sv >> 32);
    f32x4 bv = *(const f32x4*)&bs[sl*4];
    float y0 = bf2f(slo & 0xffffu) + bv[0] + a0*invd;
    float y1 = bf2f(slo >> 16)     + bv[1] + a1*invd;
    float y2 = bf2f(shi & 0xffffu) + bv[2] + a2*invd;
    float y3 = bf2f(shi >> 16)     + bv[3] + a3*invd;
    y0 = fmaxf(y0, 0.f); y1 = fmaxf(y1, 0.f);
    y2 = fmaxf(y2, 0.f); y3 = fmaxf(y3, 0.f);
    float s1 = y0 + y1 + y2 + y3;
    float s2 = y0*y0 + y1*y1 + y2*y2 + y3*y3;
    for (int off = 32; off > 0; off >>= 1){
        s1 += __shfl_xor(s1, off);
        s2 += __shfl_xor(s2, off);
    }
    float mu  = s1 * (1.f/256.f);
    float var = s2 * (1.f/256.f) - mu*mu;
    float inv = rsqrtf(var + 1e-5f);
    f32x4 gv = *(const f32x4*)&lg[sl*4];
    f32x4 lbv = *(const f32x4*)&lb[sl*4];
    float o0 = (y0 - mu)*inv*gv[0] + lbv[0];
    float o1 = (y1 - mu)*inv*gv[1] + lbv[1];
    float o2 = (y2 - mu)*inv*gv[2] + lbv[2];
    float o3 = (y3 - mu)*inv*gv[3] + lbv[3];
    if (half) return;
    if (write_f){
        *(f32x4*)(xf + (size_t)nd*DD + sl*4) = (f32x4){o0, o1, o2, o3};
    } else {
        unsigned int d0 = (unsigned int)f2bf(o0) | ((unsigned int)f2bf(o1) << 16);
        unsigned int d1 = (unsigned int)f2bf(o2) | ((unsigned int)f2bf(o3) << 16);
        int dw = (((sl >> 1) ^ (nd & 15)) << 2) + ((sl & 1) << 1);
        *((unsigned long long*)((unsigned int*)xb + (size_t)nd*64 + dw)) =
            (unsigned long long)d0 | ((unsigned long long)d1 << 32);
    }
}

// ---------------- path encoder ----------------
__global__ __launch_bounds__(256) void k_gin(const float* __restrict__ enc,
                                             const int* __restrict__ pn,
                                             const int* __restrict__ pr,
                                             const float* __restrict__ rel_emb,
                                             const float* __restrict__ Wiht,
                                             float* __restrict__ gi){
    int b = blockIdx.x;          // 0..255
    int dir = b >> 7;
    int blk = b & 127;
    int pairs0 = blk * 8;
    int tid = threadIdx.x;
    int group = tid >> 7;
    int tl = tid & 127;
    __shared__ float sq[8][256];
    for (int k = 0; k < 2; ++k){
        int idx = tid + 256*k;
        int row = idx >> 6;
        int off = (idx & 63) * 4;
        int pair = pairs0 + row;
        int p = pair >> 2, tt = pair & 3;
        int tsel = dir ? (3 - tt) : tt;
        f32x4 v;
        if (off < 128){
            int node = pn[p*4 + tsel];
            v = *(const f32x4*)&enc[(size_t)node*DD + off];
        } else if (tsel == 0){
            v = (f32x4){0.f,0.f,0.f,0.f};
        } else {
            int rel = pr[p*3 + (tsel-1)];
            v = *(const f32x4*)&rel_emb[(size_t)rel*DD + (off-128)];
        }
        *(f32x4*)&sq[row][off] = v;
    }
    __syncthreads();
    const float* W = Wiht + (size_t)dir*131072;
    float acc[4][4];
    for (int a=0;a<4;++a) for (int g=0;g<4;++g) acc[a][g]=0.f;
    for (int j4 = 0; j4 < 256; j4 += 4){
        f32x4 sv[4];
        for (int q=0;q<4;++q) sv[q] = *(const f32x4*)&sq[group*4+q][j4];
        for (int jj = 0; jj < 4; ++jj){
            int j = j4 + jj;
            float w0 = W[(size_t)j*512 + tl];
            float w1 = W[(size_t)j*512 + tl + 128];
            float w2 = W[(size_t)j*512 + tl + 256];
            float w3 = W[(size_t)j*512 + tl + 384];
            for (int q=0;q<4;++q){
                float sval = sv[q][jj];
                acc[q][0] += sval*w0;
                acc[q][1] += sval*w1;
                acc[q][2] += sval*w2;
                acc[q][3] += sval*w3;
            }
        }
    }
    for (int q=0;q<4;++q){
        int pair = pairs0 + group*4 + q;
        float* dstp = gi + ((size_t)dir*1024 + pair)*512;
        dstp[tl]     = acc[q][0];
        dstp[tl+128] = acc[q][1];
        dstp[tl+256] = acc[q][2];
        dstp[tl+384] = acc[q][3];
    }
}
__global__ __launch_bounds__(256) void k_rec(const float* __restrict__ gi,
                                             const float* __restrict__ Whht,
                                             const float* __restrict__ b_f,
                                             const float* __restrict__ b_b,
                                             float* __restrict__ hbuf){
    int b = blockIdx.x;       // 0..127
    int dir = b >> 6;
    int pg = b & 63;
    int p0 = pg * 4;
    int tid = threadIdx.x;
    int group = tid >> 7;
    int tl = tid & 127;
    __shared__ float hs[4][128], cs[4][128], gb[4][512];
    {
        int it = tid;       hs[it>>7][it&127] = 0.f; cs[it>>7][it&127] = 0.f;
        it = tid + 256;     hs[it>>7][it&127] = 0.f; cs[it>>7][it&127] = 0.f;
    }
    __syncthreads();
    const float* W = Whht + (size_t)dir*65536;
    const float* bias = dir ? b_b : b_f;
    float bb0 = bias[tl], bb1 = bias[tl+128], bb2 = bias[tl+256], bb3 = bias[tl+384];
    for (int t = 0; t < 4; ++t){
        float acc[2][4];
        for (int pl = 0; pl < 2; ++pl){
            int p = p0 + group*2 + pl;
            const float* gp = gi + ((size_t)dir*1024 + p*4 + t)*512;
            acc[pl][0] = gp[tl]     + bb0;
            acc[pl][1] = gp[tl+128] + bb1;
            acc[pl][2] = gp[tl+256] + bb2;
            acc[pl][3] = gp[tl+384] + bb3;
        }
        for (int j4 = 0; j4 < 128; j4 += 4){
            f32x4 hv0 = *(const f32x4*)&hs[group*2][j4];
            f32x4 hv1 = *(const f32x4*)&hs[group*2+1][j4];
            for (int jj = 0; jj < 4; ++jj){
                int j = j4 + jj;
                float w0 = W[(size_t)j*512 + tl];
                float w1 = W[(size_t)j*512 + tl + 128];
                float w2 = W[(size_t)j*512 + tl + 256];
                float w3 = W[(size_t)j*512 + tl + 384];
                float h0 = hv0[jj], h1 = hv1[jj];
                acc[0][0] += h0*w0; acc[0][1] += h0*w1; acc[0][2] += h0*w2; acc[0][3] += h0*w3;
                acc[1][0] += h1*w0; acc[1][1] += h1*w1; acc[1][2] += h1*w2; acc[1][3] += h1*w3;
            }
        }
        for (int pl = 0; pl < 2; ++pl){
            int pidx = group*2 + pl;
            gb[pidx][tl]     = acc[pl][0];
            gb[pidx][tl+128] = acc[pl][1];
            gb[pidx][tl+256] = acc[pl][2];
            gb[pidx][tl+384] = acc[pl][3];
        }
        __syncthreads();
        for (int r = 0; r < 2; ++r){
            int it = tid + 256*r;
            int pidx = it >> 7, k = it & 127;
            float giv = gb[pidx][k], gfv = gb[pidx][128+k], ggv = gb[pidx][256+k], gov = gb[pidx][384+k];
            float si = 1.f/(1.f + expf(-giv));
            float sf = 1.f/(1.f + expf(-gfv));
            float so = 1.f/(1.f + expf(-gov));
            float cn = sf*cs[pidx][k] + si*tanhf(ggv);
            cs[pidx][k] = cn;
            hs[pidx][k] = so*tanhf(cn);
        }
        __syncthreads();
    }
    for (int r = 0; r < 2; ++r){
        int it = tid + 256*r;
        int pidx = it >> 7, k = it & 127;
        hbuf[((size_t)dir*PP + p0 + pidx)*DD + k] = hs[pidx][k];
    }
}
__global__ __launch_bounds__(256) void k_head(const float* __restrict__ hbuf,
    const float* __restrict__ query, const float* __restrict__ Wopt, const float* __restrict__ Ws1t,
    const float* __restrict__ b_op, const float* __restrict__ b_s1,
    const float* __restrict__ W_s2, const float* __restrict__ b_s2,
    float* __restrict__ out)
{
    int pb = blockIdx.x * 8;
    int tid = threadIdx.x;
    __shared__ float cat[8][256];
    __shared__ float pe_l[8][128];
    __shared__ float hd_l[8][128];
    __shared__ float qs[128];
    __shared__ float part[8][2];
    for (int k = 0; k < 8; ++k){
        int i = tid + 256*k;
        int p = i >> 8, j = i & 255;
        float v = (j < 128) ? hbuf[(size_t)(pb+p)*DD + j]
                            : hbuf[(size_t)(PP + pb + p)*DD + (j-128)];
        cat[p][j] = v;
    }
    if (tid < 128) qs[tid] = query[tid];
    __syncthreads();
    int k = tid & 127;
    int sub = tid >> 7;
    for (int r = 0; r < 4; ++r){
        int p = sub + 2*r;
        float a = b_op[k];
        for (int j = 0; j < 256; ++j) a += Wopt[j*128 + k] * cat[p][j];
        a = fmaxf(a, 0.f);
        pe_l[p][k] = a;
        out[(size_t)NN*DD + (size_t)(pb+p)*DD + k] = a;
    }
    __syncthreads();
    for (int r = 0; r < 4; ++r){
        int p = sub + 2*r;
        float a = b_s1[k];
        for (int j = 0; j < 128; ++j) a += Ws1t[j*128 + k] * pe_l[p][j];
        for (int j = 0; j < 128; ++j) a += Ws1t[(128+j)*128 + k] * qs[j];
        hd_l[p][k] = fmaxf(a, 0.f);
    }
    __syncthreads();
    for (int r = 0; r < 4; ++r){
        int p = sub + 2*r;
        float v = W_s2[k] * hd_l[p][k];
        for (int off = 32; off > 0; off >>= 1) v += __shfl_xor(v, off);
        if ((tid & 63) == 0) part[p][(tid>>6)&1] = v;
    }
    __syncthreads();
    if (tid < 8){
        float sv = part[tid][0] + part[tid][1] + b_s2[0];
        out[(size_t)NN*DD + (size_t)PP*DD + pb + tid] = 1.f/(1.f + expf(-sv));
    }
}

extern "C" void kernel_launch(void* const* d_in, const int* in_sizes, int n_in,
                              void* d_out, int out_size, void* d_ws, size_t ws_size,
                              hipStream_t stream)
{
    (void)in_sizes; (void)n_in; (void)out_size; (void)ws_size;
    const float* nf      = (const float*)d_in[0];
    const int*   ei      = (const int*)d_in[1];
    const int*   et      = (const int*)d_in[2];
    const float* query   = (const float*)d_in[3];
    const int*   pn      = (const int*)d_in[4];
    const int*   pr      = (const int*)d_in[5];
    const float* W_self  = (const float*)d_in[6];
    const float* b_self  = (const float*)d_in[7];
    const float* W_rel   = (const float*)d_in[8];
    const float* ln_g    = (const float*)d_in[9];
    const float* ln_b    = (const float*)d_in[10];
    const float* rel_emb = (const float*)d_in[11];
    const float* W_ih_f  = (const float*)d_in[12];
    const float* W_hh_f  = (const float*)d_in[13];
    const float* b_f     = (const float*)d_in[14];
    const float* W_ih_b  = (const float*)d_in[15];
    const float* W_hh_b  = (const float*)d_in[16];
    const float* b_b     = (const float*)d_in[17];
    const float* W_op    = (const float*)d_in[18];
    const float* b_op    = (const float*)d_in[19];
    const float* W_s1    = (const float*)d_in[20];
    const float* b_s1    = (const float*)d_in[21];
    const float* W_s2    = (const float*)d_in[22];
    const float* b_s2    = (const float*)d_in[23];
    float* out = (float*)d_out;

    char* wp = (char*)d_ws;
    size_t off = 0;
    auto alloc = [&](size_t bytes)->void*{
        void* p = wp + off;
        off += (bytes + 255) & ~(size_t)255;
        return p;
    };
    int* deg        = (int*)alloc((size_t)NN*4);
    int* row_start  = (int*)alloc((size_t)(NN+1)*4);
    int* rank       = (int*)alloc((size_t)EE*4);
    int* bsum       = (int*)alloc(256*4);
    int* boff       = (int*)alloc(256*4);
    unsigned int* csr = (unsigned int*)alloc((size_t)EE*4);
    unsigned short* x0b   = (unsigned short*)alloc((size_t)PADN*DD*2);
    unsigned short* x1b   = (unsigned short*)alloc((size_t)PADN*DD*2);
    unsigned short* Bcat  = (unsigned short*)alloc((size_t)2*NSLOT*DD*DD*2);
    float* Wiht = (float*)alloc((size_t)262144*4);
    float* Whht = (float*)alloc((size_t)131072*4);
    float* Wopt = (float*)alloc((size_t)32768*4);
    float* Ws1t = (float*)alloc((size_t)32768*4);
    float* gi   = (float*)alloc((size_t)2*1024*512*4);
    float* hbuf = (float*)alloc((size_t)2*PP*DD*4);
    unsigned short* trans = (unsigned short*)alloc((size_t)NSLOT*NN*DD*2);  // slot16 = self

    hipMemsetAsync(deg, 0, (size_t)NN*4, stream);
    k_hist<<<(EE+255)/256, 256, 0, stream>>>(ei + EE, deg, rank);
    k_scan1<<<196, 256, 0, stream>>>(deg, bsum);
    k_scan2<<<1, 256, 0, stream>>>(bsum, boff);
    k_scan3<<<196, 256, 0, stream>>>(deg, boff, row_start);
    k_fused<<<NB_FILL + NB_CVT + NB_PREP, 256, 0, stream>>>(
        ei, ei + EE, et, row_start, rank, csr, nf, x0b,
        W_rel, W_self, W_ih_f, W_ih_b, W_hh_f, W_hh_b, W_op, W_s1,
        Bcat, Wiht, Whht, Wopt, Ws1t);
    for (int l = 0; l < 2; ++l){
        const unsigned short* xin = l ? x1b : x0b;
        const unsigned short* Bl  = Bcat + (size_t)l*NSLOT*DD*DD;
        k_gemm<<<PADN/64, 256, 0, stream>>>(xin, Bl, trans);
        if (l == 0)
            k_aggfin<<<PADN/4, 256, 0, stream>>>(trans, csr, row_start,
                b_self, ln_g, ln_b, nullptr, x1b, 0);
        else
            k_aggfin<<<PADN/4, 256, 0, stream>>>(trans, csr, row_start,
                b_self + DD, ln_g + DD, ln_b + DD, out, nullptr, 1);
    }
    k_gin<<<256, 256, 0, stream>>>(out, pn, pr, rel_emb, Wiht, gi);
    k_rec<<<128, 256, 0, stream>>>(gi, Whht, b_f, b_b, hbuf);
    k_head<<<32, 256, 0, stream>>>(hbuf, query, Wopt, Ws1t, b_op, b_s1, W_s2, b_s2, out);
}

// Round 10
// 484.686 us; speedup vs baseline: 1.1367x; 1.1367x over previous
//
#include <hip/hip_runtime.h>

// GraphRetriever on MI355X.
// R9 vs R8 (R8 passed @521us; R9 slot-loop regressed to 551 -- FETCH savings
// were L3-served/cheap, slot serialization cost more):
//  - k_gemm reverted to the R7/R8 128x128 form (69-75us measured),
//  - NEW: XCD-affinity remap. 1D grid 8*49*17; xcd=bid&7, m=(bid>>3)/17*8+xcd,
//    s=(bid>>3)%17. All 17 slot-blocks of an m-tile run consecutively on ONE
//    XCD -> A-tile fetched into that XCD's L2 once (per-XCD A footprint 1.6MB).
// Everything else identical to R8.

#define NN 50000
#define EE 800000
#define DD 128
#define RR 16
#define PP 256
#define PADN 50048          // 391*128
#define NSLOT 17            // 16 relations + self
#define CSTRIDE 136         // padded repack stride (shorts)

typedef __attribute__((ext_vector_type(4))) float f32x4;
typedef __attribute__((ext_vector_type(2))) float f32x2;
typedef __attribute__((ext_vector_type(8))) short s16x8;

__device__ __forceinline__ float bf2f(unsigned int u16v){
    unsigned int u = u16v << 16;
    return __builtin_bit_cast(float, u);
}
__device__ __forceinline__ unsigned short f2bf(float f){
    unsigned int u = __builtin_bit_cast(unsigned int, f);
    u = u + 0x7fffu + ((u >> 16) & 1u);
    return (unsigned short)(u >> 16);
}

// ---------------- CSR build ----------------
__global__ void k_hist(const int* __restrict__ dst, int* __restrict__ deg,
                       int* __restrict__ rank){
    int e = blockIdx.x*256 + threadIdx.x;
    if (e < EE) rank[e] = atomicAdd(&deg[dst[e]], 1);
}
__global__ void k_scan1(const int* __restrict__ deg, int* __restrict__ bsum){
    __shared__ int sm[256];
    int t = threadIdx.x, i = blockIdx.x*256 + t;
    sm[t] = (i < NN) ? deg[i] : 0;
    __syncthreads();
    for (int o = 128; o > 0; o >>= 1){
        if (t < o) sm[t] += sm[t+o];
        __syncthreads();
    }
    if (t == 0) bsum[blockIdx.x] = sm[0];
}
__global__ void k_scan2(const int* __restrict__ bsum, int* __restrict__ boff){
    __shared__ int sm[256];
    int t = threadIdx.x;
    int v = (t < 196) ? bsum[t] : 0;
    sm[t] = v;
    __syncthreads();
    for (int o = 1; o < 256; o <<= 1){
        int x = (t >= o) ? sm[t-o] : 0;
        __syncthreads();
        sm[t] += x;
        __syncthreads();
    }
    boff[t] = sm[t] - v;   // exclusive over blocks
}
__global__ void k_scan3(const int* __restrict__ deg, const int* __restrict__ boff,
                        int* __restrict__ row_start){
    __shared__ int sm[256];
    int t = threadIdx.x, i = blockIdx.x*256 + t;
    int v = (i < NN) ? deg[i] : 0;
    sm[t] = v;
    __syncthreads();
    for (int o = 1; o < 256; o <<= 1){
        int x = (t >= o) ? sm[t-o] : 0;
        __syncthreads();
        sm[t] += x;
        __syncthreads();
    }
    if (i < NN) row_start[i] = boff[blockIdx.x] + sm[t] - v;
    if (i == 0) row_start[NN] = EE;
}

// ---------------- fused: csr fill + x0 convert(+swizzle) + weight prep ----------------
#define NB_FILL 3125
#define NB_CVT  25024
#define NB_PREP 3968
__global__ void k_fused(const int* __restrict__ src, const int* __restrict__ dst,
                        const int* __restrict__ et, const int* __restrict__ row_start,
                        const int* __restrict__ rank, unsigned int* __restrict__ csr,
                        const float* __restrict__ nf, unsigned short* __restrict__ xb,
                        const float* __restrict__ W_rel, const float* __restrict__ W_self,
                        const float* __restrict__ Wihf, const float* __restrict__ Wihb,
                        const float* __restrict__ Whhf, const float* __restrict__ Whhb,
                        const float* __restrict__ Wop,  const float* __restrict__ Ws1,
                        unsigned short* __restrict__ Bcat,
                        float* __restrict__ Wiht, float* __restrict__ Whht,
                        float* __restrict__ Wopt, float* __restrict__ Ws1t){
    int b = blockIdx.x;
    if (b < NB_FILL){
        int e = b*256 + threadIdx.x;
        int pos = row_start[dst[e]] + rank[e];
        csr[pos] = ((unsigned int)et[e] << 16) | (unsigned int)src[e];  // src<50000<2^16
        return;
    }
    if (b < NB_FILL + NB_CVT){
        int i = (b - NB_FILL)*256 + threadIdx.x;   // < PADN*DD exactly
        int r  = i >> 7;
        int dd = i & 127;
        int d  = (((dd >> 3) ^ (r & 15)) << 3) | (dd & 7);   // swizzle decode
        xb[i] = (r < NN) ? f2bf(nf[(size_t)r*DD + d]) : (unsigned short)0;
        return;
    }
    int i = (b - NB_FILL - NB_CVT)*256 + threadIdx.x;
    if (i < 557056){   // Bcat[l][s][ko][dd], swizzled over dd-chunks by ko&15
        int l  = i / (NSLOT*DD*DD);
        int r  = i % (NSLOT*DD*DD);
        int s  = r / (DD*DD);
        int r2 = r % (DD*DD);
        int ko = r2 / DD;
        int dd = r2 % DD;
        int d  = (((dd >> 3) ^ (ko & 15)) << 3) | (dd & 7);
        float v = (s < RR) ? W_rel[(((size_t)(l*RR + s))*DD + d)*DD + ko]
                           : W_self[((size_t)l*DD + d)*DD + ko];
        Bcat[i] = f2bf(v);
        return;
    }
    int i2 = i - 557056;
    if (i2 < 131072){ int j=i2/512, g=i2%512; Wiht[i2] = Wihf[g*256+j]; }
    else if (i2 < 262144){ int i3=i2-131072; int j=i3/512, g=i3%512; Wiht[131072+i3] = Wihb[g*256+j]; }
    else if (i2 < 327680){ int i3=i2-262144; int j=i3/512, g=i3%512; Whht[i3] = Whhf[g*128+j]; }
    else if (i2 < 393216){ int i3=i2-327680; int j=i3/512, g=i3%512; Whht[65536+i3] = Whhb[g*128+j]; }
    else if (i2 < 425984){ int i3=i2-393216; int j=i3/128, k=i3%128; Wopt[i3] = Wop[k*256+j]; }
    else if (i2 < 458752){ int i3=i2-425984; int j=i3/128, k=i3%128; Ws1t[i3] = Ws1[k*256+j]; }
}

// ---------------- RGCN GEMM: C[s][m][ko] = sum_d A[m][d] * Bt[s][ko][d] ----------------
// A and Bt chunk-swizzled per row; C linear. XCD-affine block remap:
// xcd = bid&7; all 17 slots of one m-tile consecutive on one XCD.
__global__ __launch_bounds__(256, 2) void k_gemm(const unsigned short* __restrict__ A,
                                                 const unsigned short* __restrict__ Bt,
                                                 unsigned short* __restrict__ C)
{
    __shared__ unsigned short S[32768];         // 64KB: As | Bs; reused for padded repack
    unsigned short* As = S;
    unsigned short* Bs = S + 16384;
    const int bid = blockIdx.x;
    const int xcd = bid & 7;
    const int rr  = bid >> 3;                   // 0..832
    const int mt  = (rr / NSLOT)*8 + xcd;       // m-tile 0..391
    const int s   = rr % NSLOT;
    if (mt >= 391) return;
    const int m0 = mt * 128;
    const int tid  = threadIdx.x;
    const int wave = tid >> 6;
    const int lane = tid & 63;

    const unsigned short* gA = A + ((size_t)m0 + wave*32)*DD + lane*8;
    const unsigned short* gB = Bt + ((size_t)s*DD + wave*32)*DD + lane*8;
    unsigned short* lA = As + (wave*32)*DD;
    unsigned short* lB = Bs + (wave*32)*DD;
    for (int i = 0; i < 8; ++i){
        __builtin_amdgcn_global_load_lds((__attribute__((address_space(1))) const void*)(gA + i*512),
                                         (__attribute__((address_space(3))) void*)(lA + i*512), 16, 0, 0);
        __builtin_amdgcn_global_load_lds((__attribute__((address_space(1))) const void*)(gB + i*512),
                                         (__attribute__((address_space(3))) void*)(lB + i*512), 16, 0, 0);
    }
    __syncthreads();

    const int wm = wave & 1, wn = wave >> 1;
    f32x4 acc[4][4];
    for (int a=0;a<4;++a) for (int b=0;b<4;++b) acc[a][b] = (f32x4){0.f,0.f,0.f,0.f};

    for (int kb = 0; kb < 4; ++kb){
        const int cx = (((kb << 2) + (lane >> 4)) ^ (lane & 15)) << 3;
        s16x8 af[4], bfr[4];
        for (int mi=0;mi<4;++mi)
            af[mi] = *(const s16x8*)(As + (wm*64 + mi*16 + (lane&15))*DD + cx);
        for (int ni=0;ni<4;++ni)
            bfr[ni] = *(const s16x8*)(Bs + (wn*64 + ni*16 + (lane&15))*DD + cx);
        for (int mi=0;mi<4;++mi)
            for (int ni=0;ni<4;++ni)
                acc[mi][ni] = __builtin_amdgcn_mfma_f32_16x16x32_bf16(af[mi], bfr[ni], acc[mi][ni], 0, 0, 0);
    }
    __syncthreads();
    unsigned short* Cs = S;                     // 128*136*2 = 34816 B
    for (int mi=0;mi<4;++mi){
        int mrow0 = wm*64 + mi*16 + ((lane>>4)<<2);
        for (int ni=0;ni<4;++ni){
            int coln = wn*64 + ni*16 + (lane&15);
            for (int r=0;r<4;++r)
                Cs[(mrow0+r)*CSTRIDE + coln] = f2bf(acc[mi][ni][r]);
        }
    }
    __syncthreads();
    for (int ps = 0; ps < 8; ++ps){
        int idx = ps*256 + tid;
        int row = idx >> 4, seg = idx & 15;
        int m = m0 + row;
        if (m < NN)
            *(s16x8*)(C + ((size_t)s*NN + m)*DD + seg*8) = *(const s16x8*)(Cs + row*CSTRIDE + seg*8);
    }
}

// ---------------- fused aggregate + self + bias + relu + LayerNorm ----------------
__global__ __launch_bounds__(256) void k_aggfin(
    const unsigned short* __restrict__ trans, const unsigned int* __restrict__ csr,
    const int* __restrict__ row_start,
    const float* __restrict__ bs, const float* __restrict__ lg, const float* __restrict__ lb,
    float* __restrict__ xf, unsigned short* __restrict__ xb, int write_f)
{
    int nd = blockIdx.x*4 + (threadIdx.x >> 6);
    int lane = threadIdx.x & 63;
    int half = lane >> 5;
    int sl   = lane & 31;
    if (nd >= NN){
        if (!write_f && nd < PADN) ((unsigned int*)xb)[(size_t)nd*64 + lane] = 0u;
        return;
    }
    int rs = row_start[nd], re = row_start[nd+1];
    float a0 = 0.f, a1 = 0.f, a2 = 0.f, a3 = 0.f;
    int e = rs + half;
    for (; e + 2 < re; e += 4){
        unsigned int v1 = csr[e], v2 = csr[e+2];
        unsigned long long p1 = *((const unsigned long long*)(trans +
            ((size_t)(v1 >> 16)*NN + (v1 & 0xffffu))*DD) + sl);
        unsigned long long p2 = *((const unsigned long long*)(trans +
            ((size_t)(v2 >> 16)*NN + (v2 & 0xffffu))*DD) + sl);
        unsigned int l1 = (unsigned int)p1, h1 = (unsigned int)(p1 >> 32);
        unsigned int l2 = (unsigned int)p2, h2 = (unsigned int)(p2 >> 32);
        a0 += bf2f(l1 & 0xffffu) + bf2f(l2 & 0xffffu);
        a1 += bf2f(l1 >> 16)     + bf2f(l2 >> 16);
        a2 += bf2f(h1 & 0xffffu) + bf2f(h2 & 0xffffu);
        a3 += bf2f(h1 >> 16)     + bf2f(h2 >> 16);
    }
    if (e < re){
        unsigned int v1 = csr[e];
        unsigned long long p1 = *((const unsigned long long*)(trans +
            ((size_t)(v1 >> 16)*NN + (v1 & 0xffffu))*DD) + sl);
        unsigned int l1 = (unsigned int)p1, h1 = (unsigned int)(p1 >> 32);
        a0 += bf2f(l1 & 0xffffu);
        a1 += bf2f(l1 >> 16);
        a2 += bf2f(h1 & 0xffffu);
        a3 += bf2f(h1 >> 16);
    }
    a0 += __shfl_xor(a0, 32);
    a1 += __shfl_xor(a1, 32);
    a2 += __shfl_xor(a2, 32);
    a3 += __shfl_xor(a3, 32);

    float invd = 1.f / fmaxf((float)(re - rs), 1.f);
    unsigned long long sv = *((const unsigned long long*)(trans +
        ((size_t)16*NN + nd)*DD) + sl);
    unsigned int slo = (unsigned int)sv, shi = (unsigned int)(sv >> 32);
    f32x4 bv = *(const f32x4*)&bs[sl*4];
    float y0 = bf2f(slo & 0xffffu) + bv[0] + a0*invd;
    float y1 = bf2f(slo >> 16)     + bv[1] + a1*invd;
    float y2 = bf2f(shi & 0xffffu) + bv[2] + a2*invd;
    float y3 = bf2f(shi >> 16)     + bv[3] + a3*invd;
    y0 = fmaxf(y0, 0.f); y1 = fmaxf(y1, 0.f);
    y2 = fmaxf(y2, 0.f); y3 = fmaxf(y3, 0.f);
    float s1 = y0 + y1 + y2 + y3;
    float s2 = y0*y0 + y1*y1 + y2*y2 + y3*y3;
    for (int off = 32; off > 0; off >>= 1){
        s1 += __shfl_xor(s1, off);
        s2 += __shfl_xor(s2, off);
    }
    float mu  = s1 * (1.f/256.f);
    float var = s2 * (1.f/256.f) - mu*mu;
    float inv = rsqrtf(var + 1e-5f);
    f32x4 gv = *(const f32x4*)&lg[sl*4];
    f32x4 lbv = *(const f32x4*)&lb[sl*4];
    float o0 = (y0 - mu)*inv*gv[0] + lbv[0];
    float o1 = (y1 - mu)*inv*gv[1] + lbv[1];
    float o2 = (y2 - mu)*inv*gv[2] + lbv[2];
    float o3 = (y3 - mu)*inv*gv[3] + lbv[3];
    if (half) return;
    if (write_f){
        *(f32x4*)(xf + (size_t)nd*DD + sl*4) = (f32x4){o0, o1, o2, o3};
    } else {
        unsigned int d0 = (unsigned int)f2bf(o0) | ((unsigned int)f2bf(o1) << 16);
        unsigned int d1 = (unsigned int)f2bf(o2) | ((unsigned int)f2bf(o3) << 16);
        int dw = (((sl >> 1) ^ (nd & 15)) << 2) + ((sl & 1) << 1);
        *((unsigned long long*)((unsigned int*)xb + (size_t)nd*64 + dw)) =
            (unsigned long long)d0 | ((unsigned long long)d1 << 32);
    }
}

// ---------------- path encoder ----------------
__global__ __launch_bounds__(256) void k_gin(const float* __restrict__ enc,
                                             const int* __restrict__ pn,
                                             const int* __restrict__ pr,
                                             const float* __restrict__ rel_emb,
                                             const float* __restrict__ Wiht,
                                             float* __restrict__ gi){
    int b = blockIdx.x;          // 0..255
    int dir = b >> 7;
    int blk = b & 127;
    int pairs0 = blk * 8;
    int tid = threadIdx.x;
    int group = tid >> 7;
    int tl = tid & 127;
    __shared__ float sq[8][256];
    for (int k = 0; k < 2; ++k){
        int idx = tid + 256*k;
        int row = idx >> 6;
        int off = (idx & 63) * 4;
        int pair = pairs0 + row;
        int p = pair >> 2, tt = pair & 3;
        int tsel = dir ? (3 - tt) : tt;
        f32x4 v;
        if (off < 128){
            int node = pn[p*4 + tsel];
            v = *(const f32x4*)&enc[(size_t)node*DD + off];
        } else if (tsel == 0){
            v = (f32x4){0.f,0.f,0.f,0.f};
        } else {
            int rel = pr[p*3 + (tsel-1)];
            v = *(const f32x4*)&rel_emb[(size_t)rel*DD + (off-128)];
        }
        *(f32x4*)&sq[row][off] = v;
    }
    __syncthreads();
    const float* W = Wiht + (size_t)dir*131072;
    float acc[4][4];
    for (int a=0;a<4;++a) for (int g=0;g<4;++g) acc[a][g]=0.f;
    for (int j4 = 0; j4 < 256; j4 += 4){
        f32x4 sv[4];
        for (int q=0;q<4;++q) sv[q] = *(const f32x4*)&sq[group*4+q][j4];
        for (int jj = 0; jj < 4; ++jj){
            int j = j4 + jj;
            float w0 = W[(size_t)j*512 + tl];
            float w1 = W[(size_t)j*512 + tl + 128];
            float w2 = W[(size_t)j*512 + tl + 256];
            float w3 = W[(size_t)j*512 + tl + 384];
            for (int q=0;q<4;++q){
                float sval = sv[q][jj];
                acc[q][0] += sval*w0;
                acc[q][1] += sval*w1;
                acc[q][2] += sval*w2;
                acc[q][3] += sval*w3;
            }
        }
    }
    for (int q=0;q<4;++q){
        int pair = pairs0 + group*4 + q;
        float* dstp = gi + ((size_t)dir*1024 + pair)*512;
        dstp[tl]     = acc[q][0];
        dstp[tl+128] = acc[q][1];
        dstp[tl+256] = acc[q][2];
        dstp[tl+384] = acc[q][3];
    }
}
__global__ __launch_bounds__(256) void k_rec(const float* __restrict__ gi,
                                             const float* __restrict__ Whht,
                                             const float* __restrict__ b_f,
                                             const float* __restrict__ b_b,
                                             float* __restrict__ hbuf){
    int b = blockIdx.x;       // 0..127
    int dir = b >> 6;
    int pg = b & 63;
    int p0 = pg * 4;
    int tid = threadIdx.x;
    int group = tid >> 7;
    int tl = tid & 127;
    __shared__ float hs[4][128], cs[4][128], gb[4][512];
    {
        int it = tid;       hs[it>>7][it&127] = 0.f; cs[it>>7][it&127] = 0.f;
        it = tid + 256;     hs[it>>7][it&127] = 0.f; cs[it>>7][it&127] = 0.f;
    }
    __syncthreads();
    const float* W = Whht + (size_t)dir*65536;
    const float* bias = dir ? b_b : b_f;
    float bb0 = bias[tl], bb1 = bias[tl+128], bb2 = bias[tl+256], bb3 = bias[tl+384];
    for (int t = 0; t < 4; ++t){
        float acc[2][4];
        for (int pl = 0; pl < 2; ++pl){
            int p = p0 + group*2 + pl;
            const float* gp = gi + ((size_t)dir*1024 + p*4 + t)*512;
            acc[pl][0] = gp[tl]     + bb0;
            acc[pl][1] = gp[tl+128] + bb1;
            acc[pl][2] = gp[tl+256] + bb2;
            acc[pl][3] = gp[tl+384] + bb3;
        }
        for (int j4 = 0; j4 < 128; j4 += 4){
            f32x4 hv0 = *(const f32x4*)&hs[group*2][j4];
            f32x4 hv1 = *(const f32x4*)&hs[group*2+1][j4];
            for (int jj = 0; jj < 4; ++jj){
                int j = j4 + jj;
                float w0 = W[(size_t)j*512 + tl];
                float w1 = W[(size_t)j*512 + tl + 128];
                float w2 = W[(size_t)j*512 + tl + 256];
                float w3 = W[(size_t)j*512 + tl + 384];
                float h0 = hv0[jj], h1 = hv1[jj];
                acc[0][0] += h0*w0; acc[0][1] += h0*w1; acc[0][2] += h0*w2; acc[0][3] += h0*w3;
                acc[1][0] += h1*w0; acc[1][1] += h1*w1; acc[1][2] += h1*w2; acc[1][3] += h1*w3;
            }
        }
        for (int pl = 0; pl < 2; ++pl){
            int pidx = group*2 + pl;
            gb[pidx][tl]     = acc[pl][0];
            gb[pidx][tl+128] = acc[pl][1];
            gb[pidx][tl+256] = acc[pl][2];
            gb[pidx][tl+384] = acc[pl][3];
        }
        __syncthreads();
        for (int r = 0; r < 2; ++r){
            int it = tid + 256*r;
            int pidx = it >> 7, k = it & 127;
            float giv = gb[pidx][k], gfv = gb[pidx][128+k], ggv = gb[pidx][256+k], gov = gb[pidx][384+k];
            float si = 1.f/(1.f + expf(-giv));
            float sf = 1.f/(1.f + expf(-gfv));
            float so = 1.f/(1.f + expf(-gov));
            float cn = sf*cs[pidx][k] + si*tanhf(ggv);
            cs[pidx][k] = cn;
            hs[pidx][k] = so*tanhf(cn);
        }
        __syncthreads();
    }
    for (int r = 0; r < 2; ++r){
        int it = tid + 256*r;
        int pidx = it >> 7, k = it & 127;
        hbuf[((size_t)dir*PP + p0 + pidx)*DD + k] = hs[pidx][k];
    }
}
__global__ __launch_bounds__(256) void k_head(const float* __restrict__ hbuf,
    const float* __restrict__ query, const float* __restrict__ Wopt, const float* __restrict__ Ws1t,
    const float* __restrict__ b_op, const float* __restrict__ b_s1,
    const float* __restrict__ W_s2, const float* __restrict__ b_s2,
    float* __restrict__ out)
{
    int pb = blockIdx.x * 8;
    int tid = threadIdx.x;
    __shared__ float cat[8][256];
    __shared__ float pe_l[8][128];
    __shared__ float hd_l[8][128];
    __shared__ float qs[128];
    __shared__ float part[8][2];
    for (int k = 0; k < 8; ++k){
        int i = tid + 256*k;
        int p = i >> 8, j = i & 255;
        float v = (j < 128) ? hbuf[(size_t)(pb+p)*DD + j]
                            : hbuf[(size_t)(PP + pb + p)*DD + (j-128)];
        cat[p][j] = v;
    }
    if (tid < 128) qs[tid] = query[tid];
    __syncthreads();
    int k = tid & 127;
    int sub = tid >> 7;
    for (int r = 0; r < 4; ++r){
        int p = sub + 2*r;
        float a = b_op[k];
        for (int j = 0; j < 256; ++j) a += Wopt[j*128 + k] * cat[p][j];
        a = fmaxf(a, 0.f);
        pe_l[p][k] = a;
        out[(size_t)NN*DD + (size_t)(pb+p)*DD + k] = a;
    }
    __syncthreads();
    for (int r = 0; r < 4; ++r){
        int p = sub + 2*r;
        float a = b_s1[k];
        for (int j = 0; j < 128; ++j) a += Ws1t[j*128 + k] * pe_l[p][j];
        for (int j = 0; j < 128; ++j) a += Ws1t[(128+j)*128 + k] * qs[j];
        hd_l[p][k] = fmaxf(a, 0.f);
    }
    __syncthreads();
    for (int r = 0; r < 4; ++r){
        int p = sub + 2*r;
        float v = W_s2[k] * hd_l[p][k];
        for (int off = 32; off > 0; off >>= 1) v += __shfl_xor(v, off);
        if ((tid & 63) == 0) part[p][(tid>>6)&1] = v;
    }
    __syncthreads();
    if (tid < 8){
        float sv = part[tid][0] + part[tid][1] + b_s2[0];
        out[(size_t)NN*DD + (size_t)PP*DD + pb + tid] = 1.f/(1.f + expf(-sv));
    }
}

extern "C" void kernel_launch(void* const* d_in, const int* in_sizes, int n_in,
                              void* d_out, int out_size, void* d_ws, size_t ws_size,
                              hipStream_t stream)
{
    (void)in_sizes; (void)n_in; (void)out_size; (void)ws_size;
    const float* nf      = (const float*)d_in[0];
    const int*   ei      = (const int*)d_in[1];
    const int*   et      = (const int*)d_in[2];
    const float* query   = (const float*)d_in[3];
    const int*   pn      = (const int*)d_in[4];
    const int*   pr      = (const int*)d_in[5];
    const float* W_self  = (const float*)d_in[6];
    const float* b_self  = (const float*)d_in[7];
    const float* W_rel   = (const float*)d_in[8];
    const float* ln_g    = (const float*)d_in[9];
    const float* ln_b    = (const float*)d_in[10];
    const float* rel_emb = (const float*)d_in[11];
    const float* W_ih_f  = (const float*)d_in[12];
    const float* W_hh_f  = (const float*)d_in[13];
    const float* b_f     = (const float*)d_in[14];
    const float* W_ih_b  = (const float*)d_in[15];
    const float* W_hh_b  = (const float*)d_in[16];
    const float* b_b     = (const float*)d_in[17];
    const float* W_op    = (const float*)d_in[18];
    const float* b_op    = (const float*)d_in[19];
    const float* W_s1    = (const float*)d_in[20];
    const float* b_s1    = (const float*)d_in[21];
    const float* W_s2    = (const float*)d_in[22];
    const float* b_s2    = (const float*)d_in[23];
    float* out = (float*)d_out;

    char* wp = (char*)d_ws;
    size_t off = 0;
    auto alloc = [&](size_t bytes)->void*{
        void* p = wp + off;
        off += (bytes + 255) & ~(size_t)255;
        return p;
    };
    int* deg        = (int*)alloc((size_t)NN*4);
    int* row_start  = (int*)alloc((size_t)(NN+1)*4);
    int* rank       = (int*)alloc((size_t)EE*4);
    int* bsum       = (int*)alloc(256*4);
    int* boff       = (int*)alloc(256*4);
    unsigned int* csr = (unsigned int*)alloc((size_t)EE*4);
    unsigned short* x0b   = (unsigned short*)alloc((size_t)PADN*DD*2);
    unsigned short* x1b   = (unsigned short*)alloc((size_t)PADN*DD*2);
    unsigned short* Bcat  = (unsigned short*)alloc((size_t)2*NSLOT*DD*DD*2);
    float* Wiht = (float*)alloc((size_t)262144*4);
    float* Whht = (float*)alloc((size_t)131072*4);
    float* Wopt = (float*)alloc((size_t)32768*4);
    float* Ws1t = (float*)alloc((size_t)32768*4);
    float* gi   = (float*)alloc((size_t)2*1024*512*4);
    float* hbuf = (float*)alloc((size_t)2*PP*DD*4);
    unsigned short* trans = (unsigned short*)alloc((size_t)NSLOT*NN*DD*2);  // slot16 = self

    hipMemsetAsync(deg, 0, (size_t)NN*4, stream);
    k_hist<<<(EE+255)/256, 256, 0, stream>>>(ei + EE, deg, rank);
    k_scan1<<<196, 256, 0, stream>>>(deg, bsum);
    k_scan2<<<1, 256, 0, stream>>>(bsum, boff);
    k_scan3<<<196, 256, 0, stream>>>(deg, boff, row_start);
    k_fused<<<NB_FILL + NB_CVT + NB_PREP, 256, 0, stream>>>(
        ei, ei + EE, et, row_start, rank, csr, nf, x0b,
        W_rel, W_self, W_ih_f, W_ih_b, W_hh_f, W_hh_b, W_op, W_s1,
        Bcat, Wiht, Whht, Wopt, Ws1t);
    const int GEMM_BLOCKS = 8 * 49 * NSLOT;   // 6664; m>=391 blocks exit early
    for (int l = 0; l < 2; ++l){
        const unsigned short* xin = l ? x1b : x0b;
        const unsigned short* Bl  = Bcat + (size_t)l*NSLOT*DD*DD;
        k_gemm<<<GEMM_BLOCKS, 256, 0, stream>>>(xin, Bl, trans);
        if (l == 0)
            k_aggfin<<<PADN/4, 256, 0, stream>>>(trans, csr, row_start,
                b_self, ln_g, ln_b, nullptr, x1b, 0);
        else
            k_aggfin<<<PADN/4, 256, 0, stream>>>(trans, csr, row_start,
                b_self + DD, ln_g + DD, ln_b + DD, out, nullptr, 1);
    }
    k_gin<<<256, 256, 0, stream>>>(out, pn, pr, rel_emb, Wiht, gi);
    k_rec<<<128, 256, 0, stream>>>(gi, Whht, b_f, b_b, hbuf);
    k_head<<<32, 256, 0, stream>>>(hbuf, query, Wopt, Ws1t, b_op, b_s1, W_s2, b_s2, out);
}